// Round 1
// baseline (98.709 us; speedup 1.0000x reference)
//
#include <hip/hip_runtime.h>
#include <math.h>

#define BB 32
#define TT 128
#define NTOK 30
#define DD 512   // D_T = D_V = D_I

// ---------------- fast tanh: (1-e)/(1+e), e = exp(-2|x|) ----------------
__device__ __forceinline__ float fast_tanh(float x) {
    float e = __expf(-2.0f * fabsf(x));
    float r = (1.0f - e) * __builtin_amdgcn_rcpf(1.0f + e);
    return copysignf(r, x);
}

// ---------------- GEMM: Y[r][c] = sum_k X[r][k]*W[k][c] + bias[c] ----------------
// BM=64, BN=64, BK=16, 256 threads, 4x4 outputs per thread. rows % 64 == 0.
__global__ __launch_bounds__(256) void gemm_bias(
    const float* __restrict__ X, const float* __restrict__ W,
    const float* __restrict__ bias, float* __restrict__ Y)
{
    __shared__ float As[16][64];   // [k][row]
    __shared__ float Bs[16][64];   // [k][col]
    const int t  = threadIdx.x;
    const int bm = blockIdx.x * 64;
    const int bn = blockIdx.y * 64;
    const int rb = (t >> 4) * 4;        // output row base (0..60)
    const int cb = (t & 15) * 4;        // output col base
    const int la_r = t >> 2;            // A-load row (0..63)
    const int la_k = (t & 3) * 4;       // A-load k base
    const int lb_k = t >> 4;            // B-load k (0..15)
    const int lb_n = (t & 15) * 4;      // B-load col base

    float acc[4][4] = {};
    for (int k0 = 0; k0 < DD; k0 += 16) {
        float4 a4 = *(const float4*)&X[(size_t)(bm + la_r) * DD + k0 + la_k];
        float4 b4 = *(const float4*)&W[(size_t)(k0 + lb_k) * DD + bn + lb_n];
        __syncthreads();   // protect previous iteration's reads
        As[la_k + 0][la_r] = a4.x;
        As[la_k + 1][la_r] = a4.y;
        As[la_k + 2][la_r] = a4.z;
        As[la_k + 3][la_r] = a4.w;
        *(float4*)&Bs[lb_k][lb_n] = b4;
        __syncthreads();
        #pragma unroll
        for (int k = 0; k < 16; ++k) {
            float4 av = *(const float4*)&As[k][rb];
            float4 bv = *(const float4*)&Bs[k][cb];
            float ar[4] = {av.x, av.y, av.z, av.w};
            float br[4] = {bv.x, bv.y, bv.z, bv.w};
            #pragma unroll
            for (int i = 0; i < 4; ++i)
                #pragma unroll
                for (int j = 0; j < 4; ++j)
                    acc[i][j] += ar[i] * br[j];
        }
    }
    float4 bsv = *(const float4*)&bias[bn + cb];
    float bb4[4] = {bsv.x, bsv.y, bsv.z, bsv.w};
    #pragma unroll
    for (int i = 0; i < 4; ++i) {
        float4 o;
        o.x = acc[i][0] + bb4[0];
        o.y = acc[i][1] + bb4[1];
        o.z = acc[i][2] + bb4[2];
        o.w = acc[i][3] + bb4[3];
        *(float4*)&Y[(size_t)(bm + rb + i) * DD + bn + cb] = o;
    }
}

// ---------------- fused attend: one wave per (b,t) ----------------
__global__ __launch_bounds__(256) void attend(
    const float* __restrict__ Sbuf,   // [B][NTOK][D]
    const float* __restrict__ Vbuf,   // [B][T][D]
    const float* __restrict__ h_s,    // [B][NTOK][D]
    const int*   __restrict__ lengths,
    const float* __restrict__ W_w, const float* __restrict__ b_w,
    float* __restrict__ out)          // [B][T][D]
{
    const int wid  = (blockIdx.x * blockDim.x + threadIdx.x) >> 6;
    const int lane = threadIdx.x & 63;
    const int b = wid >> 7;          // / TT
    const int t = wid & (TT - 1);
    const int len = lengths[b];
    const int d0 = lane * 8;

    const float* Vrow = Vbuf + ((size_t)(b * TT + t)) * DD;
    const float* Srow = Sbuf + (size_t)b * NTOK * DD;

    float4 v0 = *(const float4*)&Vrow[d0];
    float4 v1 = *(const float4*)&Vrow[d0 + 4];
    float v[8] = {v0.x, v0.y, v0.z, v0.w, v1.x, v1.y, v1.z, v1.w};
    float4 w0 = *(const float4*)&W_w[d0];
    float4 w1 = *(const float4*)&W_w[d0 + 4];
    float ww[8] = {w0.x, w0.y, w0.z, w0.w, w1.x, w1.y, w1.z, w1.w};
    const float bw = b_w[0];

    float p[NTOK];
    #pragma unroll
    for (int n = 0; n < NTOK; ++n) {
        const float* Sr = Srow + (size_t)n * DD + d0;
        float4 s0 = *(const float4*)&Sr[0];
        float4 s1 = *(const float4*)&Sr[4];
        float sa[8] = {s0.x, s0.y, s0.z, s0.w, s1.x, s1.y, s1.z, s1.w};
        float acc = 0.0f;
        #pragma unroll
        for (int j = 0; j < 8; ++j)
            acc += fast_tanh(sa[j] + v[j]) * ww[j];
        #pragma unroll
        for (int off = 32; off; off >>= 1)
            acc += __shfl_xor(acc, off, 64);
        p[n] = acc + bw;
    }

    // masked softmax over n < len, renormalized (matches reference exactly)
    float mx = -1e30f;
    #pragma unroll
    for (int n = 0; n < NTOK; ++n)
        if (n < len) mx = fmaxf(mx, p[n]);
    float sum = 0.0f;
    #pragma unroll
    for (int n = 0; n < NTOK; ++n) {
        float e = (n < len) ? __expf(p[n] - mx) : 0.0f;
        p[n] = e;
        sum += e;
    }
    const float inv = 1.0f / (sum + 1e-13f);

    float acc8[8] = {};
    const float* Hrow = h_s + (size_t)b * NTOK * DD;
    #pragma unroll
    for (int n = 0; n < NTOK; ++n) {
        float a = p[n] * inv + 1e-13f;
        float4 h0 = *(const float4*)&Hrow[(size_t)n * DD + d0];
        float4 h1 = *(const float4*)&Hrow[(size_t)n * DD + d0 + 4];
        acc8[0] += a * h0.x; acc8[1] += a * h0.y;
        acc8[2] += a * h0.z; acc8[3] += a * h0.w;
        acc8[4] += a * h1.x; acc8[5] += a * h1.y;
        acc8[6] += a * h1.z; acc8[7] += a * h1.w;
    }
    float* Or = out + ((size_t)(b * TT + t)) * DD + d0;
    *(float4*)&Or[0] = make_float4(acc8[0], acc8[1], acc8[2], acc8[3]);
    *(float4*)&Or[4] = make_float4(acc8[4], acc8[5], acc8[6], acc8[7]);
}

extern "C" void kernel_launch(void* const* d_in, const int* in_sizes, int n_in,
                              void* d_out, int out_size, void* d_ws, size_t ws_size,
                              hipStream_t stream) {
    const float* h_s     = (const float*)d_in[0];
    const float* h_v     = (const float*)d_in[1];
    const int*   lengths = (const int*)  d_in[2];
    const float* W_S     = (const float*)d_in[3];
    const float* b_S     = (const float*)d_in[4];
    const float* W_V     = (const float*)d_in[5];
    const float* b_V     = (const float*)d_in[6];
    const float* W_w     = (const float*)d_in[7];
    const float* b_w     = (const float*)d_in[8];
    float* out  = (float*)d_out;

    float* Sbuf = (float*)d_ws;                       // 960*512 f32
    float* Vbuf = Sbuf + (size_t)BB * NTOK * DD;      // 4096*512 f32

    gemm_bias<<<dim3(BB * NTOK / 64, DD / 64), 256, 0, stream>>>(h_s, W_S, b_S, Sbuf);
    gemm_bias<<<dim3(BB * TT   / 64, DD / 64), 256, 0, stream>>>(h_v, W_V, b_V, Vbuf);
    attend<<<(BB * TT) / 4, 256, 0, stream>>>(Sbuf, Vbuf, h_s, lengths, W_w, b_w, out);
}

// Round 2
// 58.274 us; speedup vs baseline: 1.6939x; 1.6939x over previous
//
#include <hip/hip_runtime.h>
#include <math.h>

#define BB 32
#define TT 128
#define NTOK 30
#define DD 512   // D_T = D_V = D_I

typedef unsigned short ushortT;
typedef __attribute__((ext_vector_type(8))) short bf16x8;
typedef __attribute__((ext_vector_type(4))) float f32x4;

// ---------------- helpers ----------------
__device__ __forceinline__ ushortT f2bf(float f) {
    unsigned u = __builtin_bit_cast(unsigned, f);
    u += 0x7fffu + ((u >> 16) & 1u);          // RNE (no NaN in this data)
    return (ushortT)(u >> 16);
}

__device__ __forceinline__ float fast_tanh(float x) {
    float e = __expf(-2.0f * fabsf(x));
    float r = (1.0f - e) * __builtin_amdgcn_rcpf(1.0f + e);
    return copysignf(r, x);
}

__device__ __forceinline__ void load_lds16(const ushortT* g, ushortT* l) {
    __builtin_amdgcn_global_load_lds(
        (const __attribute__((address_space(1))) unsigned int*)g,
        (__attribute__((address_space(3))) unsigned int*)l,
        16, 0, 0);
}

// ---------------- f32 -> bf16 cast for the two activation matrices ----------------
__global__ __launch_bounds__(256) void conv_bf16_2(
    const float* __restrict__ x0, int n0_4,
    const float* __restrict__ x1, int n1_4,
    ushortT* __restrict__ y0, ushortT* __restrict__ y1)
{
    int i = blockIdx.x * 256 + threadIdx.x;
    const float* x; ushortT* y;
    if (i < n0_4) { x = x0; y = y0; }
    else { i -= n0_4; if (i >= n1_4) return; x = x1; y = y1; }
    float4 v = ((const float4*)x)[i];
    ushort4 o;
    o.x = f2bf(v.x); o.y = f2bf(v.y); o.z = f2bf(v.z); o.w = f2bf(v.w);
    ((ushort4*)y)[i] = o;
}

// ---------------- W [K][N] f32 -> W^T [N][K] bf16 (both weight matrices) ----------------
__global__ __launch_bounds__(256) void convT_bf16(
    const float* __restrict__ W0, const float* __restrict__ W1,
    ushortT* __restrict__ T0, ushortT* __restrict__ T1)
{
    __shared__ ushortT tile[32][33];
    const float* W = blockIdx.z ? W1 : W0;
    ushortT*    T  = blockIdx.z ? T1 : T0;
    int k0 = blockIdx.x * 32, n0 = blockIdx.y * 32;
    int c = threadIdx.x & 31, r8 = threadIdx.x >> 5;
    #pragma unroll
    for (int q = 0; q < 4; ++q) {
        int k = r8 + q * 8;
        tile[k][c] = f2bf(W[(size_t)(k0 + k) * DD + n0 + c]);
    }
    __syncthreads();
    #pragma unroll
    for (int q = 0; q < 4; ++q) {
        int n = r8 + q * 8;
        T[(size_t)(n0 + n) * DD + k0 + c] = tile[c][n];
    }
}

// ---------------- bf16 MFMA GEMM: Y[r][c] = sum_k A[r][k]*W[k][c] + bias[c] ----------------
// A: [M][512] bf16 row-major (k-contig). Bt: [512][512] bf16 = W^T (k-contig).
// 64x64 block tile, 4 waves 2x2 (wave tile 32x32), BK=64.
// LDS tiles [64 rows][64 k] bf16, XOR-swizzled: 16B-chunk c of row r lives at chunk c^(r&7).
__global__ __launch_bounds__(256) void gemm_mfma(
    const ushortT* __restrict__ A, const ushortT* __restrict__ Bt,
    const float* __restrict__ bias, float* __restrict__ Y)
{
    __shared__ ushortT ldsA[64 * 64];
    __shared__ ushortT ldsB[64 * 64];
    const int tid  = threadIdx.x;
    const int lane = tid & 63;
    const int wid  = tid >> 6;
    const int wr = wid >> 1, wc = wid & 1;
    const int bm = blockIdx.x * 64;
    const int bn = blockIdx.y * 64;

    // staging: issue q in {0,1}: LDS byte (q*256+tid)*16 holds row=(q*256+tid)/8,
    // swizzled chunk ((q*256+tid)&7); its logical chunk is that ^ (row&7).
    const int idx0 = tid,       row0 = idx0 >> 3, ch0 = (idx0 & 7) ^ (row0 & 7);
    const int idx1 = 256 + tid, row1 = idx1 >> 3, ch1 = (idx1 & 7) ^ (row1 & 7);
    const ushortT* gA0 = A  + (size_t)(bm + row0) * DD + ch0 * 8;
    const ushortT* gA1 = A  + (size_t)(bm + row1) * DD + ch1 * 8;
    const ushortT* gB0 = Bt + (size_t)(bn + row0) * DD + ch0 * 8;
    const ushortT* gB1 = Bt + (size_t)(bn + row1) * DD + ch1 * 8;
    ushortT* lA0 = ldsA + wid * 512;         // wave-uniform base, lane*16B implicit
    ushortT* lA1 = ldsA + 2048 + wid * 512;
    ushortT* lB0 = ldsB + wid * 512;
    ushortT* lB1 = ldsB + 2048 + wid * 512;

    const int arow = wr * 32 + (lane & 15);  // + i*16
    const int brow = wc * 32 + (lane & 15);  // + j*16
    const int kq   = lane >> 4;
    const int sw   = lane & 7;               // == row&7 for fragment rows

    f32x4 acc[2][2];
    #pragma unroll
    for (int i = 0; i < 2; ++i)
        #pragma unroll
        for (int j = 0; j < 2; ++j)
            acc[i][j] = (f32x4){0.f, 0.f, 0.f, 0.f};

    for (int k0 = 0; k0 < DD; k0 += 64) {
        __syncthreads();                     // previous tile fully consumed
        load_lds16(gA0 + k0, lA0);
        load_lds16(gA1 + k0, lA1);
        load_lds16(gB0 + k0, lB0);
        load_lds16(gB1 + k0, lB1);
        __syncthreads();                     // vmcnt(0) drain before barrier -> data ready

        bf16x8 af[2][2], bfr[2][2];
        #pragma unroll
        for (int i = 0; i < 2; ++i)
            #pragma unroll
            for (int s = 0; s < 2; ++s) {
                int ra = arow + i * 16;
                af[i][s]  = *(const bf16x8*)(ldsA + ra * 64 + ((s * 4 + kq) ^ sw) * 8);
                int rb = brow + i * 16;
                bfr[i][s] = *(const bf16x8*)(ldsB + rb * 64 + ((s * 4 + kq) ^ sw) * 8);
            }
        #pragma unroll
        for (int s = 0; s < 2; ++s)
            #pragma unroll
            for (int i = 0; i < 2; ++i)
                #pragma unroll
                for (int j = 0; j < 2; ++j)
                    acc[i][j] = __builtin_amdgcn_mfma_f32_16x16x32_bf16(
                        af[i][s], bfr[j][s], acc[i][j], 0, 0, 0);
    }

    // D layout: col = lane&15, row = (lane>>4)*4 + reg
    #pragma unroll
    for (int i = 0; i < 2; ++i)
        #pragma unroll
        for (int j = 0; j < 2; ++j) {
            int r = bm + wr * 32 + i * 16 + (lane >> 4) * 4;
            int c = bn + wc * 32 + j * 16 + (lane & 15);
            float bv = bias[c];
            #pragma unroll
            for (int reg = 0; reg < 4; ++reg)
                Y[(size_t)(r + reg) * DD + c] = acc[i][j][reg] + bv;
        }
}

// ---------------- fused attend: one wave per (b,t) ----------------
__global__ __launch_bounds__(256) void attend(
    const float* __restrict__ Sbuf, const float* __restrict__ Vbuf,
    const float* __restrict__ h_s, const int* __restrict__ lengths,
    const float* __restrict__ W_w, const float* __restrict__ b_w,
    float* __restrict__ out)
{
    const int wid  = (blockIdx.x * blockDim.x + threadIdx.x) >> 6;
    const int lane = threadIdx.x & 63;
    const int b = wid >> 7;
    const int t = wid & (TT - 1);
    const int len = lengths[b];
    const int d0 = lane * 8;

    const float* Vrow = Vbuf + ((size_t)(b * TT + t)) * DD;
    const float* Srow = Sbuf + (size_t)b * NTOK * DD;

    float4 v0 = *(const float4*)&Vrow[d0];
    float4 v1 = *(const float4*)&Vrow[d0 + 4];
    float v[8] = {v0.x, v0.y, v0.z, v0.w, v1.x, v1.y, v1.z, v1.w};
    float4 w0 = *(const float4*)&W_w[d0];
    float4 w1 = *(const float4*)&W_w[d0 + 4];
    float ww[8] = {w0.x, w0.y, w0.z, w0.w, w1.x, w1.y, w1.z, w1.w};
    const float bw = b_w[0];

    float p[NTOK];
    #pragma unroll
    for (int n = 0; n < NTOK; ++n) {
        const float* Sr = Srow + (size_t)n * DD + d0;
        float4 s0 = *(const float4*)&Sr[0];
        float4 s1 = *(const float4*)&Sr[4];
        float sa[8] = {s0.x, s0.y, s0.z, s0.w, s1.x, s1.y, s1.z, s1.w};
        float acc = 0.0f;
        #pragma unroll
        for (int j = 0; j < 8; ++j)
            acc += fast_tanh(sa[j] + v[j]) * ww[j];
        #pragma unroll
        for (int off = 32; off; off >>= 1)
            acc += __shfl_xor(acc, off, 64);
        p[n] = acc + bw;
    }

    float mx = -1e30f;
    #pragma unroll
    for (int n = 0; n < NTOK; ++n)
        if (n < len) mx = fmaxf(mx, p[n]);
    float sum = 0.0f;
    #pragma unroll
    for (int n = 0; n < NTOK; ++n) {
        float e = (n < len) ? __expf(p[n] - mx) : 0.0f;
        p[n] = e;
        sum += e;
    }
    const float inv = 1.0f / (sum + 1e-13f);

    float acc8[8] = {};
    const float* Hrow = h_s + (size_t)b * NTOK * DD;
    #pragma unroll
    for (int n = 0; n < NTOK; ++n) {
        float a = p[n] * inv + 1e-13f;
        float4 h0 = *(const float4*)&Hrow[(size_t)n * DD + d0];
        float4 h1 = *(const float4*)&Hrow[(size_t)n * DD + d0 + 4];
        acc8[0] += a * h0.x; acc8[1] += a * h0.y;
        acc8[2] += a * h0.z; acc8[3] += a * h0.w;
        acc8[4] += a * h1.x; acc8[5] += a * h1.y;
        acc8[6] += a * h1.z; acc8[7] += a * h1.w;
    }
    float* Or = out + ((size_t)(b * TT + t)) * DD + d0;
    *(float4*)&Or[0] = make_float4(acc8[0], acc8[1], acc8[2], acc8[3]);
    *(float4*)&Or[4] = make_float4(acc8[4], acc8[5], acc8[6], acc8[7]);
}

extern "C" void kernel_launch(void* const* d_in, const int* in_sizes, int n_in,
                              void* d_out, int out_size, void* d_ws, size_t ws_size,
                              hipStream_t stream) {
    const float* h_s     = (const float*)d_in[0];
    const float* h_v     = (const float*)d_in[1];
    const int*   lengths = (const int*)  d_in[2];
    const float* W_S     = (const float*)d_in[3];
    const float* b_S     = (const float*)d_in[4];
    const float* W_V     = (const float*)d_in[5];
    const float* b_V     = (const float*)d_in[6];
    const float* W_w     = (const float*)d_in[7];
    const float* b_w     = (const float*)d_in[8];
    float* out = (float*)d_out;

    // workspace layout
    float*   Sbuf  = (float*)d_ws;                               // 960*512 f32
    float*   Vbuf  = Sbuf + (size_t)BB * NTOK * DD;              // 4096*512 f32
    ushortT* Abf_s = (ushortT*)(Vbuf + (size_t)BB * TT * DD);    // 960*512 bf16
    ushortT* Abf_v = Abf_s + (size_t)BB * NTOK * DD;             // 4096*512 bf16
    ushortT* WtS   = Abf_v + (size_t)BB * TT * DD;               // 512*512 bf16
    ushortT* WtV   = WtS + (size_t)DD * DD;                      // 512*512 bf16

    const int n0_4 = BB * NTOK * DD / 4;   // 122880
    const int n1_4 = BB * TT * DD / 4;     // 524288
    conv_bf16_2<<<(n0_4 + n1_4 + 255) / 256, 256, 0, stream>>>(
        h_s, n0_4, h_v, n1_4, Abf_s, Abf_v);
    convT_bf16<<<dim3(DD / 32, DD / 32, 2), 256, 0, stream>>>(W_S, W_V, WtS, WtV);

    gemm_mfma<<<dim3(BB * NTOK / 64, DD / 64), 256, 0, stream>>>(Abf_s, WtS, b_S, Sbuf);
    gemm_mfma<<<dim3(BB * TT / 64, DD / 64), 256, 0, stream>>>(Abf_v, WtV, b_V, Vbuf);

    attend<<<(BB * TT) / 4, 256, 0, stream>>>(Sbuf, Vbuf, h_s, lengths, W_w, b_w, out);
}

// Round 3
// 44.174 us; speedup vs baseline: 2.2346x; 1.3192x over previous
//
#include <hip/hip_runtime.h>
#include <math.h>

#define BB 32
#define TT 128
#define NTOK 30
#define DD 512
#define C2F 2.885390081777927f   // 2*log2(e): tanh(x) = 1 - 2/(1+2^(C2F*x))

typedef unsigned short ushortT;
typedef __attribute__((ext_vector_type(8))) short bf16x8;
typedef __attribute__((ext_vector_type(4))) float f32x4;

__device__ __forceinline__ ushortT f2bf(float f) {
    unsigned u = __builtin_bit_cast(unsigned, f);
    u += 0x7fffu + ((u >> 16) & 1u);          // RNE
    return (ushortT)(u >> 16);
}

__device__ __forceinline__ void load_lds16(const ushortT* g, ushortT* l) {
    __builtin_amdgcn_global_load_lds(
        (const __attribute__((address_space(1))) unsigned int*)g,
        (__attribute__((address_space(3))) unsigned int*)l,
        16, 0, 0);
}

// ---------------- prep: bf16 casts + W transposes, one dispatch ----------------
#define NCONV ((BB*NTOK*DD + BB*TT*DD)/4/256)   // 5056 blocks
__global__ __launch_bounds__(256) void prep(
    const float* __restrict__ h_s, const float* __restrict__ h_v,
    const float* __restrict__ W_S, const float* __restrict__ W_V,
    ushortT* __restrict__ Abf_s, ushortT* __restrict__ Abf_v,
    ushortT* __restrict__ WtS, ushortT* __restrict__ WtV)
{
    __shared__ ushortT tile[32][33];
    int bx = blockIdx.x;
    if (bx < NCONV) {
        int i = bx * 256 + threadIdx.x;
        const int n0_4 = BB * NTOK * DD / 4;
        const float* x; ushortT* y;
        if (i < n0_4) { x = h_s; y = Abf_s; }
        else { i -= n0_4; x = h_v; y = Abf_v; }
        float4 v = ((const float4*)x)[i];
        ushort4 o;
        o.x = f2bf(v.x); o.y = f2bf(v.y); o.z = f2bf(v.z); o.w = f2bf(v.w);
        ((ushort4*)y)[i] = o;
        return;
    }
    int idx = bx - NCONV;                        // 0..511
    const float* W = (idx & 256) ? W_V : W_S;
    ushortT*    T  = (idx & 256) ? WtV : WtS;
    idx &= 255;
    int k0 = (idx >> 4) * 32, n0 = (idx & 15) * 32;
    int c = threadIdx.x & 31, r8 = threadIdx.x >> 5;
    #pragma unroll
    for (int q = 0; q < 4; ++q) {
        int k = r8 + q * 8;
        tile[k][c] = f2bf(W[(size_t)(k0 + k) * DD + n0 + c]);
    }
    __syncthreads();
    #pragma unroll
    for (int q = 0; q < 4; ++q) {
        int n = r8 + q * 8;
        T[(size_t)(n0 + n) * DD + k0 + c] = tile[c][n];
    }
}

// ---------------- bf16 MFMA GEMM, both matrices in one dispatch ----------------
// Y = (A @ W + bias) * C2F   (pre-scaled for the tanh in attend)
__global__ __launch_bounds__(256) void gemm_mfma(
    const ushortT* __restrict__ Abf_s, const ushortT* __restrict__ Abf_v,
    const ushortT* __restrict__ WtS, const ushortT* __restrict__ WtV,
    const float* __restrict__ b_S, const float* __restrict__ b_V,
    float* __restrict__ Sbuf, float* __restrict__ Vbuf)
{
    __shared__ ushortT ldsA[64 * 64];
    __shared__ ushortT ldsB[64 * 64];
    const ushortT* A; const ushortT* Bt; const float* bias; float* Y; int bm;
    if (blockIdx.x < 15) { A = Abf_s; Bt = WtS; bias = b_S; Y = Sbuf; bm = blockIdx.x * 64; }
    else                 { A = Abf_v; Bt = WtV; bias = b_V; Y = Vbuf; bm = (blockIdx.x - 15) * 64; }

    const int tid  = threadIdx.x;
    const int lane = tid & 63;
    const int wid  = tid >> 6;
    const int wr = wid >> 1, wc = wid & 1;
    const int bn = blockIdx.y * 64;

    const int idx0 = tid,       row0 = idx0 >> 3, ch0 = (idx0 & 7) ^ (row0 & 7);
    const int idx1 = 256 + tid, row1 = idx1 >> 3, ch1 = (idx1 & 7) ^ (row1 & 7);
    const ushortT* gA0 = A  + (size_t)(bm + row0) * DD + ch0 * 8;
    const ushortT* gA1 = A  + (size_t)(bm + row1) * DD + ch1 * 8;
    const ushortT* gB0 = Bt + (size_t)(bn + row0) * DD + ch0 * 8;
    const ushortT* gB1 = Bt + (size_t)(bn + row1) * DD + ch1 * 8;
    ushortT* lA0 = ldsA + wid * 512;
    ushortT* lA1 = ldsA + 2048 + wid * 512;
    ushortT* lB0 = ldsB + wid * 512;
    ushortT* lB1 = ldsB + 2048 + wid * 512;

    const int arow = wr * 32 + (lane & 15);
    const int brow = wc * 32 + (lane & 15);
    const int kq   = lane >> 4;
    const int sw   = lane & 7;

    f32x4 acc[2][2];
    #pragma unroll
    for (int i = 0; i < 2; ++i)
        #pragma unroll
        for (int j = 0; j < 2; ++j)
            acc[i][j] = (f32x4){0.f, 0.f, 0.f, 0.f};

    for (int k0 = 0; k0 < DD; k0 += 64) {
        __syncthreads();
        load_lds16(gA0 + k0, lA0);
        load_lds16(gA1 + k0, lA1);
        load_lds16(gB0 + k0, lB0);
        load_lds16(gB1 + k0, lB1);
        __syncthreads();

        bf16x8 af[2][2], bfr[2][2];
        #pragma unroll
        for (int i = 0; i < 2; ++i)
            #pragma unroll
            for (int s = 0; s < 2; ++s) {
                int ra = arow + i * 16;
                af[i][s]  = *(const bf16x8*)(ldsA + ra * 64 + ((s * 4 + kq) ^ sw) * 8);
                int rb = brow + i * 16;
                bfr[i][s] = *(const bf16x8*)(ldsB + rb * 64 + ((s * 4 + kq) ^ sw) * 8);
            }
        #pragma unroll
        for (int s = 0; s < 2; ++s)
            #pragma unroll
            for (int i = 0; i < 2; ++i)
                #pragma unroll
                for (int j = 0; j < 2; ++j)
                    acc[i][j] = __builtin_amdgcn_mfma_f32_16x16x32_bf16(
                        af[i][s], bfr[j][s], acc[i][j], 0, 0, 0);
    }

    #pragma unroll
    for (int i = 0; i < 2; ++i)
        #pragma unroll
        for (int j = 0; j < 2; ++j) {
            int r = bm + wr * 32 + i * 16 + (lane >> 4) * 4;
            int c = bn + wc * 32 + j * 16 + (lane & 15);
            float bv = bias[c];
            #pragma unroll
            for (int reg = 0; reg < 4; ++reg)
                Y[(size_t)(r + reg) * DD + c] = (acc[i][j][reg] + bv) * C2F;
        }
}

// ---------------- attend: block per (b, 16-t chunk), S[b] staged in LDS ----------------
__global__ __launch_bounds__(512) void attend2(
    const float* __restrict__ Sbuf, const float* __restrict__ Vbuf,
    const float* __restrict__ h_s, const int* __restrict__ lengths,
    const float* __restrict__ W_w, const float* __restrict__ b_w,
    float* __restrict__ out)
{
    __shared__ float Slds[NTOK * DD];             // 61440 B; reused for h_s
    const int b  = blockIdx.x >> 3;
    const int tc = blockIdx.x & 7;
    const int tid = threadIdx.x;
    const int t  = tid >> 5;                      // 0..15
    const int dg = tid & 31;                      // 0..31
    const int t_glob = tc * 16 + t;
    const int len = lengths[b];
    const float bwv = b_w[0];

    // stage S[b] (pre-scaled by C2F in gemm)
    const float4* sSrc = (const float4*)(Sbuf + (size_t)b * NTOK * DD);
    float4* sDst = (float4*)Slds;
    #pragma unroll
    for (int i = 0; i < 8; ++i) {
        int idx = i * 512 + tid;
        if (idx < NTOK * DD / 4) sDst[idx] = sSrc[idx];
    }

    // V (pre-scaled) and W_w into regs: this thread's cols = dg*4 + 128*c
    const float* Vrow = Vbuf + ((size_t)(b * TT + t_glob)) * DD;
    float4 v4[4], w4[4];
    #pragma unroll
    for (int c = 0; c < 4; ++c) {
        v4[c] = *(const float4*)&Vrow[dg * 4 + 128 * c];
        w4[c] = *(const float4*)&W_w[dg * 4 + 128 * c];
    }
    float wsum = 0.f;
    #pragma unroll
    for (int c = 0; c < 4; ++c) wsum += w4[c].x + w4[c].y + w4[c].z + w4[c].w;

    __syncthreads();

    // beta partials: pacc[n] = sum_d w_d * rcp(1 + 2^(S'+V'))  over this thread's 16 d
    float pacc[NTOK];
    #pragma unroll
    for (int n = 0; n < NTOK; ++n) {
        const float* Sr = Slds + n * DD;
        float a = 0.f;
        #pragma unroll
        for (int c = 0; c < 4; ++c) {
            float4 s4 = *(const float4*)&Sr[dg * 4 + 128 * c];
            a = fmaf(w4[c].x, __builtin_amdgcn_rcpf(1.f + __builtin_amdgcn_exp2f(s4.x + v4[c].x)), a);
            a = fmaf(w4[c].y, __builtin_amdgcn_rcpf(1.f + __builtin_amdgcn_exp2f(s4.y + v4[c].y)), a);
            a = fmaf(w4[c].z, __builtin_amdgcn_rcpf(1.f + __builtin_amdgcn_exp2f(s4.z + v4[c].z)), a);
            a = fmaf(w4[c].w, __builtin_amdgcn_rcpf(1.f + __builtin_amdgcn_exp2f(s4.w + v4[c].w)), a);
        }
        pacc[n] = a;
    }
    __syncthreads();   // all S reads done -> Slds reusable

    // reduce over the 32 lanes of this t-group
    #pragma unroll
    for (int off = 1; off <= 16; off <<= 1) {
        wsum += __shfl_xor(wsum, off, 64);
        #pragma unroll
        for (int n = 0; n < NTOK; ++n) pacc[n] += __shfl_xor(pacc[n], off, 64);
    }

    // beta[n] = wsum + b_w - 2*pacc[n]; masked softmax; alpha
    float mx = -1e30f;
    #pragma unroll
    for (int n = 0; n < NTOK; ++n) {
        float bn = wsum + bwv - 2.f * pacc[n];
        pacc[n] = bn;
        if (n < len) mx = fmaxf(mx, bn);
    }
    float ssum = 0.f;
    #pragma unroll
    for (int n = 0; n < NTOK; ++n) {
        float e = (n < len) ? __expf(pacc[n] - mx) : 0.f;
        pacc[n] = e;
        ssum += e;
    }
    const float inv = 1.f / (ssum + 1e-13f);
    #pragma unroll
    for (int n = 0; n < NTOK; ++n) pacc[n] = pacc[n] * inv + 1e-13f;

    // restage h_s[b] (raw f32) into the same LDS
    const float4* hSrc = (const float4*)(h_s + (size_t)b * NTOK * DD);
    #pragma unroll
    for (int i = 0; i < 8; ++i) {
        int idx = i * 512 + tid;
        if (idx < NTOK * DD / 4) sDst[idx] = hSrc[idx];
    }
    __syncthreads();

    // out[t] = sum_n alpha[n] * h_s[n]
    float4 acc[4];
    #pragma unroll
    for (int c = 0; c < 4; ++c) acc[c] = make_float4(0.f, 0.f, 0.f, 0.f);
    #pragma unroll
    for (int n = 0; n < NTOK; ++n) {
        float a = pacc[n];
        #pragma unroll
        for (int c = 0; c < 4; ++c) {
            float4 h = *(const float4*)&Slds[n * DD + dg * 4 + 128 * c];
            acc[c].x = fmaf(a, h.x, acc[c].x);
            acc[c].y = fmaf(a, h.y, acc[c].y);
            acc[c].z = fmaf(a, h.z, acc[c].z);
            acc[c].w = fmaf(a, h.w, acc[c].w);
        }
    }
    float* Or = out + ((size_t)(b * TT + t_glob)) * DD;
    #pragma unroll
    for (int c = 0; c < 4; ++c)
        *(float4*)&Or[dg * 4 + 128 * c] = acc[c];
}

extern "C" void kernel_launch(void* const* d_in, const int* in_sizes, int n_in,
                              void* d_out, int out_size, void* d_ws, size_t ws_size,
                              hipStream_t stream) {
    const float* h_s     = (const float*)d_in[0];
    const float* h_v     = (const float*)d_in[1];
    const int*   lengths = (const int*)  d_in[2];
    const float* W_S     = (const float*)d_in[3];
    const float* b_S     = (const float*)d_in[4];
    const float* W_V     = (const float*)d_in[5];
    const float* b_V     = (const float*)d_in[6];
    const float* W_w     = (const float*)d_in[7];
    const float* b_w     = (const float*)d_in[8];
    float* out = (float*)d_out;

    float*   Sbuf  = (float*)d_ws;                               // 960*512 f32
    float*   Vbuf  = Sbuf + (size_t)BB * NTOK * DD;              // 4096*512 f32
    ushortT* Abf_s = (ushortT*)(Vbuf + (size_t)BB * TT * DD);    // 960*512 bf16
    ushortT* Abf_v = Abf_s + (size_t)BB * NTOK * DD;             // 4096*512 bf16
    ushortT* WtS   = Abf_v + (size_t)BB * TT * DD;               // 512*512 bf16
    ushortT* WtV   = WtS + (size_t)DD * DD;                      // 512*512 bf16

    prep<<<NCONV + 512, 256, 0, stream>>>(h_s, h_v, W_S, W_V, Abf_s, Abf_v, WtS, WtV);
    gemm_mfma<<<dim3(15 + 64, DD / 64), 256, 0, stream>>>(
        Abf_s, Abf_v, WtS, WtV, b_S, b_V, Sbuf, Vbuf);
    attend2<<<BB * 8, 512, 0, stream>>>(Sbuf, Vbuf, h_s, lengths, W_w, b_w, out);
}